// Round 11
// baseline (73.653 us; speedup 1.0000x reference)
//
#include <hip/hip_runtime.h>
#include <hip/hip_bf16.h>

// E=1024, H=16, P=64, B=2, S=2048. All f32 in/out.
// Six-kernel pipeline combining measured-fast halves (r5 tail + r10 head):
//  K1 prep_sk  (384): Wp split-K x8 MFMA partials, TRANSPOSED store
//  K2 wpfix2x  (257): reduce 8 slices -> WpT bf16 planes | Weff from RW | lam
//  K3 qkv2     (192): full-K per block; q -> final bf16 planes (+bias), k/v -> f32
//  K4 mpart2   (128): 32-row-chunk k^T v partials
//  K5 meffgk    (32): Meff reduce inline + G = Meff @ Weff -> GT bf16 planes
//  K6 outk    (1024): out = Q @ G via MFMA
// Split-bf16 MFMA: A*B ~= Ahi*Bhi + Ahi*Blo + Alo*Bhi (rel err ~1e-4).
// History: r4=60.9 (split-K qkv tail), r5 tail alone ~30us, r9 cooperative=399 (dead end).

typedef __attribute__((ext_vector_type(8))) short short8;
typedef __attribute__((ext_vector_type(4))) float f32x4;
typedef unsigned short ushort_t;
typedef unsigned int uint_t;

__device__ inline ushort_t f2bf(float v) {
    uint_t u = __float_as_uint(v);
    return (ushort_t)((u + 0x7FFF + ((u >> 16) & 1)) >> 16);   // RNE
}
__device__ inline float bf2f(ushort_t h) { return __uint_as_float(((uint_t)h) << 16); }
__device__ inline void split2(float v, ushort_t& hi, ushort_t& lo) {
    hi = f2bf(v);
    lo = f2bf(v - bf2f(hi));
}
__device__ inline int swzA(int row, int k) { return (row * 64 + k) ^ ((row & 7) << 3); }

// ================= workspace layout (f32 offsets) =================
#define WS_PTRS(ws) \
    float* wppartT = (ws); \
    float* kbuf    = (ws) + 1572864; \
    float* vbuf    = (ws) + 1835008; \
    float* Mpart   = (ws) + 2097152; \
    float* Weff    = (ws) + 2621440; \
    float* lamp    = (ws) + 2686976; \
    ushort_t* ub   = (ushort_t*)((ws) + 2686992); \
    ushort_t* WpThi = ub; \
    ushort_t* WpTlo = ub + 196608; \
    ushort_t* Qhi   = ub + 393216; \
    ushort_t* Qlo   = ub + 655360; \
    ushort_t* GThi  = ub + 917504; \
    ushort_t* GTlo  = ub + 1048576;

// ---- K1: Wp split-K x8 partials (transposed store). grid 384 = slice(8)xz(3)xrowblk(16)
__global__ __launch_bounds__(256) void prep_sk(
    const float* __restrict__ WQ, const float* __restrict__ WK, const float* __restrict__ WV,
    const float* __restrict__ proj_w, float* __restrict__ ws)
{
    __shared__ __align__(16) ushort_t Ah[4096], Al[4096], Bh[4096], Bl[4096];
    WS_PTRS(ws)
    (void)kbuf; (void)vbuf; (void)Mpart; (void)Weff; (void)lamp;
    (void)WpThi; (void)WpTlo; (void)Qhi; (void)Qlo; (void)GThi; (void)GTlo;
    int bid = blockIdx.x;
    int slice = bid / 48, t = bid % 48, z = t / 16, rowblk = t % 16;
    const float* A = ((z == 0) ? WQ : (z == 1) ? WK : WV) + (long long)rowblk * 64 * 1024;

    int tid = threadIdx.x;
    int wave = tid >> 6, lane = tid & 63;
    int rl = lane & 15, kg = lane >> 4;
    f32x4 acc[4] = {};

    int k0 = slice * 128;
    for (int ch = 0; ch < 2; ++ch, k0 += 64) {
        #pragma unroll
        for (int i = 0; i < 4; ++i) {
            int pos = tid + 256 * i;
            int r = pos >> 4, k4 = (pos & 15) * 4;
            float4 v = *(const float4*)&A[(long long)r * 1024 + k0 + k4];
            ushort4 h, l;
            split2(v.x, h.x, l.x); split2(v.y, h.y, l.y);
            split2(v.z, h.z, l.z); split2(v.w, h.w, l.w);
            int idx = swzA(r, k4);
            *(ushort4*)&Ah[idx] = h;
            *(ushort4*)&Al[idx] = l;
        }
        #pragma unroll
        for (int i = 0; i < 4; ++i) {
            int pos = tid + 256 * i;
            int kk = pos >> 4, n4 = (pos & 15) * 4;
            float4 v = *(const float4*)&proj_w[(long long)(k0 + kk) * 64 + n4];
            float vv[4] = {v.x, v.y, v.z, v.w};
            #pragma unroll
            for (int j = 0; j < 4; ++j) {
                ushort_t h, l; split2(vv[j], h, l);
                int idx = swzA(n4 + j, kk);
                Bh[idx] = h; Bl[idx] = l;
            }
        }
        __syncthreads();
        int ar = wave * 16 + rl;
        #pragma unroll
        for (int ks = 0; ks < 2; ++ks) {
            int kb = ks * 32 + kg * 8;
            short8 ah = *(const short8*)&Ah[swzA(ar, kb)];
            short8 al = *(const short8*)&Al[swzA(ar, kb)];
            #pragma unroll
            for (int n = 0; n < 4; ++n) {
                int bi = swzA(n * 16 + rl, kb);
                short8 bh = *(const short8*)&Bh[bi];
                short8 bl = *(const short8*)&Bl[bi];
                acc[n] = __builtin_amdgcn_mfma_f32_16x16x32_bf16(ah, bh, acc[n], 0, 0, 0);
                acc[n] = __builtin_amdgcn_mfma_f32_16x16x32_bf16(ah, bl, acc[n], 0, 0, 0);
                acc[n] = __builtin_amdgcn_mfma_f32_16x16x32_bf16(al, bh, acc[n], 0, 0, 0);
            }
        }
        __syncthreads();
    }
    // transposed store: wppartT[slice][(z*64 + col)][rowblk*64 + row], j contiguous
    #pragma unroll
    for (int n = 0; n < 4; ++n) {
        int col = n * 16 + rl;
        float4 o = {acc[n][0], acc[n][1], acc[n][2], acc[n][3]};
        long long idx = (long long)slice * 196608 + (long long)(z * 64 + col) * 1024
                      + rowblk * 64 + wave * 16 + kg * 4;
        *(float4*)&wppartT[idx] = o;
    }
}

// ---- K2: WpT plane reduce (192) + Weff (64) + lam (1). grid 257.
__global__ __launch_bounds__(256) void wpfix2x(
    const float* __restrict__ RW,
    const float* __restrict__ q1v, const float* __restrict__ k1v,
    const float* __restrict__ q2v, const float* __restrict__ k2v,
    const float* __restrict__ lam0, float* __restrict__ ws)
{
    __shared__ float red[2][4];
    WS_PTRS(ws)
    (void)kbuf; (void)vbuf; (void)Mpart; (void)Qhi; (void)Qlo; (void)GThi; (void)GTlo;
    int t = blockIdx.x, tid = threadIdx.x;
    if (t < 192) {
        int idx = t * 256 + tid;                // 49152 f4 over [192][1024]
        long long off = (long long)idx * 4;
        float4 s = {0.f, 0.f, 0.f, 0.f};
        #pragma unroll
        for (int sl = 0; sl < 8; ++sl) {
            float4 m = *(const float4*)&wppartT[(long long)sl * 196608 + off];
            s.x += m.x; s.y += m.y; s.z += m.z; s.w += m.w;
        }
        ushort4 h, l;
        split2(s.x, h.x, l.x); split2(s.y, h.y, l.y);
        split2(s.z, h.z, l.z); split2(s.w, h.w, l.w);
        *(ushort4*)&WpThi[off] = h;
        *(ushort4*)&WpTlo[off] = l;
    } else if (t < 256) {
        int f4i = (t - 192) * 256 + tid;        // 16384 f4 over Weff[64][1024]
        int p = f4i >> 8, e4 = (f4i & 255) * 4;
        float4 s = {0.f, 0.f, 0.f, 0.f};
        #pragma unroll
        for (int h = 0; h < 16; ++h) {
            float4 r = *(const float4*)&RW[(long long)(h * 64 + p) * 1024 + e4];
            float m = (float)(h + 1);
            s.x += m * r.x; s.y += m * r.y; s.z += m * r.z; s.w += m * r.w;
        }
        *(float4*)&Weff[(long long)p * 1024 + e4] = s;
    } else {
        float d1 = 0.f, d2 = 0.f;
        for (int i = tid; i < 1024; i += 256) {
            d1 += q1v[i] * k1v[i];
            d2 += q2v[i] * k2v[i];
        }
        #pragma unroll
        for (int off = 32; off > 0; off >>= 1) {
            d1 += __shfl_down(d1, off);
            d2 += __shfl_down(d2, off);
        }
        if ((tid & 63) == 0) { red[0][tid >> 6] = d1; red[1][tid >> 6] = d2; }
        __syncthreads();
        if (tid == 0) {
            float s1 = red[0][0] + red[0][1] + red[0][2] + red[0][3];
            float s2 = red[1][0] + red[1][1] + red[1][2] + red[1][3];
            lamp[0] = expf(s1) - expf(s2) + lam0[0];
        }
    }
}

// ---- K3: q,k,v full-K per block (reg-prefetch dbuf). grid 192 = z(3) x rowblk(64).
__global__ __launch_bounds__(256) void qkv2(
    const float* __restrict__ x, const float* __restrict__ proj_b,
    float* __restrict__ ws)
{
    __shared__ __align__(16) ushort_t Ah[4096], Al[4096], Bh[4096], Bl[4096];
    WS_PTRS(ws)
    (void)wppartT; (void)Mpart; (void)Weff; (void)lamp; (void)GThi; (void)GTlo;
    int bid = blockIdx.x, tid = threadIdx.x;
    int z = bid >> 6, rowblk = bid & 63;
    long long row0 = (long long)rowblk * 64;
    int wave = tid >> 6, lane = tid & 63, rl = lane & 15, kg = lane >> 4;
    f32x4 acc[4] = {};
    float4 av[4];
    short8 pbh[2], pbl[2];
    #pragma unroll
    for (int i = 0; i < 4; ++i) {
        int pos = tid + 256 * i;
        int r = pos >> 4, c4 = (pos & 15) * 4;
        av[i] = *(const float4*)&x[(row0 + r) * 1024 + c4];
    }
    #pragma unroll
    for (int i = 0; i < 2; ++i) {
        int pos = tid + 256 * i;
        int n = pos >> 3, k8 = (pos & 7) * 8;
        long long src = (long long)(z * 64 + n) * 1024 + k8;
        pbh[i] = *(const short8*)&WpThi[src];
        pbl[i] = *(const short8*)&WpTlo[src];
    }
    for (int ch = 0; ch < 16; ++ch) {
        #pragma unroll
        for (int i = 0; i < 4; ++i) {
            int pos = tid + 256 * i;
            int r = pos >> 4, c4 = (pos & 15) * 4;
            ushort4 h, l;
            split2(av[i].x, h.x, l.x); split2(av[i].y, h.y, l.y);
            split2(av[i].z, h.z, l.z); split2(av[i].w, h.w, l.w);
            int idx = swzA(r, c4);
            *(ushort4*)&Ah[idx] = h;
            *(ushort4*)&Al[idx] = l;
        }
        #pragma unroll
        for (int i = 0; i < 2; ++i) {
            int pos = tid + 256 * i;
            int n = pos >> 3, k8 = (pos & 7) * 8;
            int idx = swzA(n, k8);
            *(short8*)&Bh[idx] = pbh[i];
            *(short8*)&Bl[idx] = pbl[i];
        }
        __syncthreads();
        if (ch < 15) {
            int k0 = (ch + 1) * 64;
            #pragma unroll
            for (int i = 0; i < 4; ++i) {
                int pos = tid + 256 * i;
                int r = pos >> 4, c4 = (pos & 15) * 4;
                av[i] = *(const float4*)&x[(row0 + r) * 1024 + k0 + c4];
            }
            #pragma unroll
            for (int i = 0; i < 2; ++i) {
                int pos = tid + 256 * i;
                int n = pos >> 3, k8 = (pos & 7) * 8;
                long long src = (long long)(z * 64 + n) * 1024 + k0 + k8;
                pbh[i] = *(const short8*)&WpThi[src];
                pbl[i] = *(const short8*)&WpTlo[src];
            }
        }
        int ar = wave * 16 + rl;
        #pragma unroll
        for (int ks = 0; ks < 2; ++ks) {
            int kb = ks * 32 + kg * 8;
            short8 ah = *(const short8*)&Ah[swzA(ar, kb)];
            short8 al = *(const short8*)&Al[swzA(ar, kb)];
            #pragma unroll
            for (int n = 0; n < 4; ++n) {
                int bi = swzA(n * 16 + rl, kb);
                short8 bh = *(const short8*)&Bh[bi];
                short8 bl = *(const short8*)&Bl[bi];
                acc[n] = __builtin_amdgcn_mfma_f32_16x16x32_bf16(ah, bh, acc[n], 0, 0, 0);
                acc[n] = __builtin_amdgcn_mfma_f32_16x16x32_bf16(ah, bl, acc[n], 0, 0, 0);
                acc[n] = __builtin_amdgcn_mfma_f32_16x16x32_bf16(al, bh, acc[n], 0, 0, 0);
            }
        }
        __builtin_amdgcn_s_barrier();
    }
    #pragma unroll
    for (int n = 0; n < 4; ++n) {
        int col = n * 16 + rl;
        float bb = proj_b[col];
        #pragma unroll
        for (int j = 0; j < 4; ++j) {
            long long row = row0 + wave * 16 + kg * 4 + j;
            float val = acc[n][j] + bb;
            if (z == 0) {
                ushort_t h, l; split2(val, h, l);
                Qhi[row * 64 + col] = h;
                Qlo[row * 64 + col] = l;
            } else if (z == 1) {
                kbuf[row * 64 + col] = val;
            } else {
                vbuf[row * 64 + col] = val;
            }
        }
    }
}

// ---- K4: Mpart[b][sc][c][p] over 32-row chunks. grid 128 = sc(64) x b(2).
__global__ __launch_bounds__(256) void mpart2(float* __restrict__ ws)
{
    __shared__ float ksh[32][68], vsh[32][68];
    WS_PTRS(ws)
    (void)wppartT; (void)Weff; (void)lamp; (void)WpThi; (void)WpTlo;
    (void)Qhi; (void)Qlo; (void)GThi; (void)GTlo;
    int bid = blockIdx.x;
    int sc = bid & 63, b = bid >> 6;
    int tid = threadIdx.x;
    long long row0 = (long long)b * 2048 + sc * 32;
    #pragma unroll
    for (int i = 0; i < 4; ++i) {
        int pos = tid + 256 * i;        // 1024: arr(2) x r(32) x c4(16)
        int arr = pos >> 9, rem = pos & 511;
        int r = rem >> 4, c4 = (rem & 15) * 4;
        const float* src = (arr ? vbuf : kbuf) + (row0 + r) * 64 + c4;
        float4 v = *(const float4*)src;
        if (arr == 0) *(float4*)&ksh[r][c4] = v;
        else          *(float4*)&vsh[r][c4] = v;
    }
    __syncthreads();
    int p = tid & 63, cg = tid >> 6;
    float acc[16] = {};
    for (int s = 0; s < 32; ++s) {
        float vv = vsh[s][p];
        float4 k0 = *(const float4*)&ksh[s][cg * 16];
        float4 k1 = *(const float4*)&ksh[s][cg * 16 + 4];
        float4 k2 = *(const float4*)&ksh[s][cg * 16 + 8];
        float4 k3 = *(const float4*)&ksh[s][cg * 16 + 12];
        acc[0] += k0.x * vv;  acc[1] += k0.y * vv;  acc[2] += k0.z * vv;  acc[3] += k0.w * vv;
        acc[4] += k1.x * vv;  acc[5] += k1.y * vv;  acc[6] += k1.z * vv;  acc[7] += k1.w * vv;
        acc[8] += k2.x * vv;  acc[9] += k2.y * vv;  acc[10] += k2.z * vv; acc[11] += k2.w * vv;
        acc[12] += k3.x * vv; acc[13] += k3.y * vv; acc[14] += k3.z * vv; acc[15] += k3.w * vv;
    }
    float* o = Mpart + ((long long)b * 64 + sc) * 4096;
    #pragma unroll
    for (int ci = 0; ci < 16; ++ci)
        o[(cg * 16 + ci) * 64 + p] = acc[ci];
}

// ---- K5: Meff reduce inline + G = Meff @ Weff -> GT planes. grid 32.
__global__ __launch_bounds__(256) void meffgk(float* __restrict__ ws)
{
    __shared__ float As[64][68], Bs[64][68];
    WS_PTRS(ws)
    (void)wppartT; (void)kbuf; (void)vbuf; (void)WpThi; (void)WpTlo; (void)Qhi; (void)Qlo;
    int t = blockIdx.x, tid = threadIdx.x;
    int colblk = t & 15, b = t >> 4;
    float lam = lamp[0];
    #pragma unroll
    for (int i = 0; i < 4; ++i) {
        int pos = tid + 256 * i;            // 1024 f4 over Meff[64 c][64 p]
        int c = pos >> 4, p4 = (pos & 15) * 4;
        float4 s = {0.f, 0.f, 0.f, 0.f};
        #pragma unroll 8
        for (int sc = 0; sc < 64; ++sc) {
            float4 m = *(const float4*)&Mpart[((long long)b * 64 + sc) * 4096 + c * 64 + p4];
            s.x += m.x; s.y += m.y; s.z += m.z; s.w += m.w;
        }
        float coef = 0.125f * (c < 32 ? 1.0f : -lam);
        s.x *= coef; s.y *= coef; s.z *= coef; s.w *= coef;
        *(float4*)&As[c][p4] = s;
    }
    #pragma unroll
    for (int i = 0; i < 4; ++i) {
        int pos = tid + 256 * i;
        int p = pos >> 4, e4 = (pos & 15) * 4;
        *(float4*)&Bs[p][e4] = *(const float4*)&Weff[(long long)p * 1024 + colblk * 64 + e4];
    }
    __syncthreads();
    int tx = tid & 15, ty = tid >> 4;
    float acc[4][4] = {};
    #pragma unroll 4
    for (int kk4 = 0; kk4 < 64; kk4 += 4) {
        float4 a4[4], b4[4];
        #pragma unroll
        for (int i = 0; i < 4; ++i) a4[i] = *(const float4*)&As[ty * 4 + i][kk4];
        #pragma unroll
        for (int r = 0; r < 4; ++r) b4[r] = *(const float4*)&Bs[kk4 + r][tx * 4];
        #pragma unroll
        for (int i = 0; i < 4; ++i) {
            acc[i][0] += a4[i].x * b4[0].x + a4[i].y * b4[1].x + a4[i].z * b4[2].x + a4[i].w * b4[3].x;
            acc[i][1] += a4[i].x * b4[0].y + a4[i].y * b4[1].y + a4[i].z * b4[2].y + a4[i].w * b4[3].y;
            acc[i][2] += a4[i].x * b4[0].z + a4[i].y * b4[1].z + a4[i].z * b4[2].z + a4[i].w * b4[3].z;
            acc[i][3] += a4[i].x * b4[0].w + a4[i].y * b4[1].w + a4[i].z * b4[2].w + a4[i].w * b4[3].w;
        }
    }
    #pragma unroll
    for (int i = 0; i < 4; ++i)
        #pragma unroll
        for (int j = 0; j < 4; ++j) {
            ushort_t h, l; split2(acc[i][j], h, l);
            long long idx = (long long)b * 65536 + (long long)(colblk * 64 + tx * 4 + j) * 64 + ty * 4 + i;
            GThi[idx] = h; GTlo[idx] = l;
        }
}

// ---- K6: out = Q @ G. grid 1024.
__global__ __launch_bounds__(256) void outk(float* __restrict__ ws, float* __restrict__ out)
{
    __shared__ __align__(16) ushort_t Ah[4096], Al[4096], Bh[4096], Bl[4096];
    WS_PTRS(ws)
    (void)wppartT; (void)kbuf; (void)vbuf; (void)Mpart; (void)Weff; (void)lamp;
    (void)WpThi; (void)WpTlo;
    int bid = blockIdx.x;
    int rowblk = bid & 31, colblk = (bid >> 5) & 15, b = bid >> 9;
    int tid = threadIdx.x;
    long long row0 = (long long)b * 2048 + rowblk * 64;

    #pragma unroll
    for (int i = 0; i < 2; ++i) {
        int pos = tid + 256 * i;
        int n = pos >> 3, k8 = (pos & 7) * 8;
        int idx = swzA(n, k8);
        long long qsrc = (row0 + n) * 64 + k8;
        long long gsrc = (long long)b * 65536 + (long long)(colblk * 64 + n) * 64 + k8;
        *(short8*)&Ah[idx] = *(const short8*)&Qhi[qsrc];
        *(short8*)&Al[idx] = *(const short8*)&Qlo[qsrc];
        *(short8*)&Bh[idx] = *(const short8*)&GThi[gsrc];
        *(short8*)&Bl[idx] = *(const short8*)&GTlo[gsrc];
    }
    __syncthreads();

    int wave = tid >> 6, lane = tid & 63;
    int rl = lane & 15, kg = lane >> 4;
    f32x4 acc[4] = {};
    int ar = wave * 16 + rl;
    #pragma unroll
    for (int ks = 0; ks < 2; ++ks) {
        int kb = ks * 32 + kg * 8;
        short8 ah = *(const short8*)&Ah[swzA(ar, kb)];
        short8 al = *(const short8*)&Al[swzA(ar, kb)];
        #pragma unroll
        for (int n = 0; n < 4; ++n) {
            int bi = swzA(n * 16 + rl, kb);
            short8 bh = *(const short8*)&Bh[bi];
            short8 bl = *(const short8*)&Bl[bi];
            acc[n] = __builtin_amdgcn_mfma_f32_16x16x32_bf16(ah, bh, acc[n], 0, 0, 0);
            acc[n] = __builtin_amdgcn_mfma_f32_16x16x32_bf16(ah, bl, acc[n], 0, 0, 0);
            acc[n] = __builtin_amdgcn_mfma_f32_16x16x32_bf16(al, bh, acc[n], 0, 0, 0);
        }
    }
    #pragma unroll
    for (int n = 0; n < 4; ++n) {
        int col = colblk * 64 + n * 16 + rl;
        #pragma unroll
        for (int j = 0; j < 4; ++j) {
            int row = rowblk * 64 + wave * 16 + kg * 4 + j;
            out[(long long)b * 2097152 + (long long)row * 1024 + col] = acc[n][j];
        }
    }
}

// ================= launch =================
extern "C" void kernel_launch(void* const* d_in, const int* in_sizes, int n_in,
                              void* d_out, int out_size, void* d_ws, size_t ws_size,
                              hipStream_t stream)
{
    const float* x      = (const float*)d_in[0];
    const float* WQ     = (const float*)d_in[1];
    const float* WK     = (const float*)d_in[2];
    const float* WV     = (const float*)d_in[3];
    const float* RW     = (const float*)d_in[4];
    const float* proj_w = (const float*)d_in[5];
    const float* proj_b = (const float*)d_in[6];
    const float* q1v    = (const float*)d_in[7];
    const float* k1v    = (const float*)d_in[8];
    const float* q2v    = (const float*)d_in[9];
    const float* k2v    = (const float*)d_in[10];
    const float* lam0   = (const float*)d_in[11];
    float* ws  = (float*)d_ws;
    float* out = (float*)d_out;

    dim3 blk(256);
    prep_sk<<<dim3(384), blk, 0, stream>>>(WQ, WK, WV, proj_w, ws);
    wpfix2x<<<dim3(257), blk, 0, stream>>>(RW, q1v, k1v, q2v, k2v, lam0, ws);
    qkv2<<<dim3(192), blk, 0, stream>>>(x, proj_b, ws);
    mpart2<<<dim3(128), blk, 0, stream>>>(ws);
    meffgk<<<dim3(32), blk, 0, stream>>>(ws);
    outk<<<dim3(1024), blk, 0, stream>>>(ws, out);
}

// Round 12
// 61.275 us; speedup vs baseline: 1.2020x; 1.2020x over previous
//
#include <hip/hip_runtime.h>
#include <hip/hip_bf16.h>

// E=1024, H=16, P=64, B=2, S=2048. All f32 in/out.
// r4-best structure (60.9us) + split-K x4 qkv (halved qpart traffic) + reg prefetch:
//  K1 prep_sk  (384): Wp split-K x8 MFMA partials, TRANSPOSED store
//  K2 wpfix2x  (257): reduce 8 slices -> WpT bf16 planes | Weff from RW | lam
//  K3 qkv_f    (256): z-fused split-K x4 (4 chunks, 1 blk/CU, reg prefetch) -> qpart
//  K4 mpartq    (96): M 64-row chunks (k/v 4-slice reduce + bias) + Q plane reduce
//  K5 gkern     (32): Meff reduce (32 chunks) + G = Meff @ Weff -> GT bf16 planes
//  K6 outk    (1024): out = Q @ G via MFMA
// Split-bf16 MFMA: A*B ~= Ahi*Bhi + Ahi*Blo + Alo*Bhi (rel err ~1e-4).
// Measured dead ends: cooperative megakernel (r9: 399us), full-K qkv (r5/r11: +7-13us).

typedef __attribute__((ext_vector_type(8))) short short8;
typedef __attribute__((ext_vector_type(4))) float f32x4;
typedef unsigned short ushort_t;
typedef unsigned int uint_t;

__device__ inline ushort_t f2bf(float v) {
    uint_t u = __float_as_uint(v);
    return (ushort_t)((u + 0x7FFF + ((u >> 16) & 1)) >> 16);   // RNE
}
__device__ inline float bf2f(ushort_t h) { return __uint_as_float(((uint_t)h) << 16); }
__device__ inline void split2(float v, ushort_t& hi, ushort_t& lo) {
    hi = f2bf(v);
    lo = f2bf(v - bf2f(hi));
}
__device__ inline int swzA(int row, int k) { return (row * 64 + k) ^ ((row & 7) << 3); }

// ================= workspace layout (f32 offsets) =================
#define WS_PTRS(ws) \
    float* wppartT = (ws); \
    float* qpart   = (ws) + 1572864; \
    float* Mpart   = (ws) + 4718592; \
    float* Weff    = (ws) + 4980736; \
    float* lamp    = (ws) + 5046272; \
    ushort_t* ub   = (ushort_t*)((ws) + 5046288); \
    ushort_t* WpThi = ub; \
    ushort_t* WpTlo = ub + 196608; \
    ushort_t* Qhi   = ub + 393216; \
    ushort_t* Qlo   = ub + 655360; \
    ushort_t* GThi  = ub + 917504; \
    ushort_t* GTlo  = ub + 1048576;

// ---- K1: Wp split-K x8 partials (transposed store). grid 384 = slice(8)xz(3)xrowblk(16)
__global__ __launch_bounds__(256) void prep_sk(
    const float* __restrict__ WQ, const float* __restrict__ WK, const float* __restrict__ WV,
    const float* __restrict__ proj_w, float* __restrict__ ws)
{
    __shared__ __align__(16) ushort_t Ah[4096], Al[4096], Bh[4096], Bl[4096];
    WS_PTRS(ws)
    (void)qpart; (void)Mpart; (void)Weff; (void)lamp;
    (void)WpThi; (void)WpTlo; (void)Qhi; (void)Qlo; (void)GThi; (void)GTlo;
    int bid = blockIdx.x;
    int slice = bid / 48, t = bid % 48, z = t / 16, rowblk = t % 16;
    const float* A = ((z == 0) ? WQ : (z == 1) ? WK : WV) + (long long)rowblk * 64 * 1024;

    int tid = threadIdx.x;
    int wave = tid >> 6, lane = tid & 63;
    int rl = lane & 15, kg = lane >> 4;
    f32x4 acc[4] = {};

    int k0 = slice * 128;
    for (int ch = 0; ch < 2; ++ch, k0 += 64) {
        #pragma unroll
        for (int i = 0; i < 4; ++i) {
            int pos = tid + 256 * i;
            int r = pos >> 4, k4 = (pos & 15) * 4;
            float4 v = *(const float4*)&A[(long long)r * 1024 + k0 + k4];
            ushort4 h, l;
            split2(v.x, h.x, l.x); split2(v.y, h.y, l.y);
            split2(v.z, h.z, l.z); split2(v.w, h.w, l.w);
            int idx = swzA(r, k4);
            *(ushort4*)&Ah[idx] = h;
            *(ushort4*)&Al[idx] = l;
        }
        #pragma unroll
        for (int i = 0; i < 4; ++i) {
            int pos = tid + 256 * i;
            int kk = pos >> 4, n4 = (pos & 15) * 4;
            float4 v = *(const float4*)&proj_w[(long long)(k0 + kk) * 64 + n4];
            float vv[4] = {v.x, v.y, v.z, v.w};
            #pragma unroll
            for (int j = 0; j < 4; ++j) {
                ushort_t h, l; split2(vv[j], h, l);
                int idx = swzA(n4 + j, kk);
                Bh[idx] = h; Bl[idx] = l;
            }
        }
        __syncthreads();
        int ar = wave * 16 + rl;
        #pragma unroll
        for (int ks = 0; ks < 2; ++ks) {
            int kb = ks * 32 + kg * 8;
            short8 ah = *(const short8*)&Ah[swzA(ar, kb)];
            short8 al = *(const short8*)&Al[swzA(ar, kb)];
            #pragma unroll
            for (int n = 0; n < 4; ++n) {
                int bi = swzA(n * 16 + rl, kb);
                short8 bh = *(const short8*)&Bh[bi];
                short8 bl = *(const short8*)&Bl[bi];
                acc[n] = __builtin_amdgcn_mfma_f32_16x16x32_bf16(ah, bh, acc[n], 0, 0, 0);
                acc[n] = __builtin_amdgcn_mfma_f32_16x16x32_bf16(ah, bl, acc[n], 0, 0, 0);
                acc[n] = __builtin_amdgcn_mfma_f32_16x16x32_bf16(al, bh, acc[n], 0, 0, 0);
            }
        }
        __syncthreads();
    }
    // transposed store: wppartT[slice][(z*64 + col)][rowblk*64 + row], j contiguous
    #pragma unroll
    for (int n = 0; n < 4; ++n) {
        int col = n * 16 + rl;
        float4 o = {acc[n][0], acc[n][1], acc[n][2], acc[n][3]};
        long long idx = (long long)slice * 196608 + (long long)(z * 64 + col) * 1024
                      + rowblk * 64 + wave * 16 + kg * 4;
        *(float4*)&wppartT[idx] = o;
    }
}

// ---- K2: WpT plane reduce (192) + Weff (64) + lam (1). grid 257.
__global__ __launch_bounds__(256) void wpfix2x(
    const float* __restrict__ RW,
    const float* __restrict__ q1v, const float* __restrict__ k1v,
    const float* __restrict__ q2v, const float* __restrict__ k2v,
    const float* __restrict__ lam0, float* __restrict__ ws)
{
    __shared__ float red[2][4];
    WS_PTRS(ws)
    (void)qpart; (void)Mpart; (void)Qhi; (void)Qlo; (void)GThi; (void)GTlo;
    int t = blockIdx.x, tid = threadIdx.x;
    if (t < 192) {
        int idx = t * 256 + tid;                // 49152 f4 over [192][1024]
        long long off = (long long)idx * 4;
        float4 s = {0.f, 0.f, 0.f, 0.f};
        #pragma unroll
        for (int sl = 0; sl < 8; ++sl) {
            float4 m = *(const float4*)&wppartT[(long long)sl * 196608 + off];
            s.x += m.x; s.y += m.y; s.z += m.z; s.w += m.w;
        }
        ushort4 h, l;
        split2(s.x, h.x, l.x); split2(s.y, h.y, l.y);
        split2(s.z, h.z, l.z); split2(s.w, h.w, l.w);
        *(ushort4*)&WpThi[off] = h;
        *(ushort4*)&WpTlo[off] = l;
    } else if (t < 256) {
        int f4i = (t - 192) * 256 + tid;        // 16384 f4 over Weff[64][1024]
        int p = f4i >> 8, e4 = (f4i & 255) * 4;
        float4 s = {0.f, 0.f, 0.f, 0.f};
        #pragma unroll
        for (int h = 0; h < 16; ++h) {
            float4 r = *(const float4*)&RW[(long long)(h * 64 + p) * 1024 + e4];
            float m = (float)(h + 1);
            s.x += m * r.x; s.y += m * r.y; s.z += m * r.z; s.w += m * r.w;
        }
        *(float4*)&Weff[(long long)p * 1024 + e4] = s;
    } else {
        float d1 = 0.f, d2 = 0.f;
        for (int i = tid; i < 1024; i += 256) {
            d1 += q1v[i] * k1v[i];
            d2 += q2v[i] * k2v[i];
        }
        #pragma unroll
        for (int off = 32; off > 0; off >>= 1) {
            d1 += __shfl_down(d1, off);
            d2 += __shfl_down(d2, off);
        }
        if ((tid & 63) == 0) { red[0][tid >> 6] = d1; red[1][tid >> 6] = d2; }
        __syncthreads();
        if (tid == 0) {
            float s1 = red[0][0] + red[0][1] + red[0][2] + red[0][3];
            float s2 = red[1][0] + red[1][1] + red[1][2] + red[1][3];
            lamp[0] = expf(s1) - expf(s2) + lam0[0];
        }
    }
}

// ---- K3: qkv z-fused split-K x4 with reg prefetch. grid 256 = rowblk(64) + 64*slice(4).
__global__ __launch_bounds__(256) void qkv_f(
    const float* __restrict__ x, float* __restrict__ ws)
{
    __shared__ __align__(16) char smem[65536];
    WS_PTRS(ws)
    (void)wppartT; (void)Mpart; (void)Weff; (void)lamp; (void)Qhi; (void)Qlo; (void)GThi; (void)GTlo;
    ushort_t* Ah = (ushort_t*)smem;
    ushort_t* Al = (ushort_t*)(smem + 8192);
    ushort_t (*Bh)[4096] = (ushort_t(*)[4096])(smem + 16384);
    ushort_t (*Bl)[4096] = (ushort_t(*)[4096])(smem + 40960);
    int bid = blockIdx.x, tid = threadIdx.x;
    int wave = tid >> 6, lane = tid & 63, rl = lane & 15, kg = lane >> 4;
    int rowblk = bid & 63, slice = bid >> 6;
    long long row0 = (long long)rowblk * 64;
    f32x4 acc[3][4] = {};

    float4 av[4];
    short8 pbh[3][2], pbl[3][2];
    int k0 = slice * 256;
    #pragma unroll
    for (int i = 0; i < 4; ++i) {
        int pos = tid + 256 * i;
        int r = pos >> 4, k4 = (pos & 15) * 4;
        av[i] = *(const float4*)&x[(row0 + r) * 1024 + k0 + k4];
    }
    #pragma unroll
    for (int z = 0; z < 3; ++z)
        #pragma unroll
        for (int i = 0; i < 2; ++i) {
            int pos = tid + 256 * i;
            int n = pos >> 3, k8 = (pos & 7) * 8;
            long long src = (long long)(z * 64 + n) * 1024 + k0 + k8;
            pbh[z][i] = *(const short8*)&WpThi[src];
            pbl[z][i] = *(const short8*)&WpTlo[src];
        }

    for (int ch = 0; ch < 4; ++ch) {
        #pragma unroll
        for (int i = 0; i < 4; ++i) {
            int pos = tid + 256 * i;
            int r = pos >> 4, k4 = (pos & 15) * 4;
            ushort4 h, l;
            split2(av[i].x, h.x, l.x); split2(av[i].y, h.y, l.y);
            split2(av[i].z, h.z, l.z); split2(av[i].w, h.w, l.w);
            int idx = swzA(r, k4);
            *(ushort4*)&Ah[idx] = h;
            *(ushort4*)&Al[idx] = l;
        }
        #pragma unroll
        for (int z = 0; z < 3; ++z)
            #pragma unroll
            for (int i = 0; i < 2; ++i) {
                int pos = tid + 256 * i;
                int n = pos >> 3, k8 = (pos & 7) * 8;
                int idx = swzA(n, k8);
                *(short8*)&Bh[z][idx] = pbh[z][i];
                *(short8*)&Bl[z][idx] = pbl[z][i];
            }
        __syncthreads();
        if (ch < 3) {
            int kn = k0 + (ch + 1) * 64;
            #pragma unroll
            for (int i = 0; i < 4; ++i) {
                int pos = tid + 256 * i;
                int r = pos >> 4, k4 = (pos & 15) * 4;
                av[i] = *(const float4*)&x[(row0 + r) * 1024 + kn + k4];
            }
            #pragma unroll
            for (int z = 0; z < 3; ++z)
                #pragma unroll
                for (int i = 0; i < 2; ++i) {
                    int pos = tid + 256 * i;
                    int n = pos >> 3, k8 = (pos & 7) * 8;
                    long long src = (long long)(z * 64 + n) * 1024 + kn + k8;
                    pbh[z][i] = *(const short8*)&WpThi[src];
                    pbl[z][i] = *(const short8*)&WpTlo[src];
                }
        }
        int ar = wave * 16 + rl;
        #pragma unroll
        for (int ks = 0; ks < 2; ++ks) {
            int kb = ks * 32 + kg * 8;
            short8 ah = *(const short8*)&Ah[swzA(ar, kb)];
            short8 al = *(const short8*)&Al[swzA(ar, kb)];
            #pragma unroll
            for (int z = 0; z < 3; ++z) {
                #pragma unroll
                for (int n = 0; n < 4; ++n) {
                    int bi = swzA(n * 16 + rl, kb);
                    short8 bh = *(const short8*)&Bh[z][bi];
                    short8 bl = *(const short8*)&Bl[z][bi];
                    acc[z][n] = __builtin_amdgcn_mfma_f32_16x16x32_bf16(ah, bh, acc[z][n], 0, 0, 0);
                    acc[z][n] = __builtin_amdgcn_mfma_f32_16x16x32_bf16(ah, bl, acc[z][n], 0, 0, 0);
                    acc[z][n] = __builtin_amdgcn_mfma_f32_16x16x32_bf16(al, bh, acc[z][n], 0, 0, 0);
                }
            }
        }
        __builtin_amdgcn_s_barrier();
    }
    #pragma unroll
    for (int z = 0; z < 3; ++z) {
        float* C = qpart + (long long)(slice * 3 + z) * 262144;
        #pragma unroll
        for (int n = 0; n < 4; ++n) {
            int col = n * 16 + rl;
            #pragma unroll
            for (int j = 0; j < 4; ++j) {
                long long row = row0 + wave * 16 + kg * 4 + j;
                C[row * 64 + col] = acc[z][n][j];
            }
        }
    }
}

// ---- K4: M 64-row chunks (64 tasks, 4-slice reduce) + Q plane reduce (32). grid 96.
__global__ __launch_bounds__(256) void mpartq(
    const float* __restrict__ proj_b, float* __restrict__ ws)
{
    __shared__ __align__(16) char smem[34816];
    WS_PTRS(ws)
    (void)wppartT; (void)Weff; (void)lamp; (void)WpThi; (void)WpTlo; (void)GThi; (void)GTlo;
    int t = blockIdx.x, tid = threadIdx.x;
    if (t < 64) {
        float (*ksh)[68] = (float(*)[68])smem;
        float (*vsh)[68] = (float(*)[68])(smem + 17408);
        int ks = t & 31, b = t >> 5;
        long long row0 = (long long)b * 2048 + ks * 64;
        #pragma unroll
        for (int i = 0; i < 8; ++i) {
            int pos = tid + 256 * i;        // [arr(2)][row(64)][c4(16)]
            int arr = pos >> 10, rem = pos & 1023;
            int r = rem >> 4, c4 = (rem & 15) * 4;
            float4 s = *(const float4*)&proj_b[c4];
            long long off = (row0 + r) * 64 + c4;
            #pragma unroll
            for (int sl = 0; sl < 4; ++sl) {
                float4 m = *(const float4*)&qpart[(long long)(sl * 3 + 1 + arr) * 262144 + off];
                s.x += m.x; s.y += m.y; s.z += m.z; s.w += m.w;
            }
            if (arr == 0) *(float4*)&ksh[r][c4] = s;
            else          *(float4*)&vsh[r][c4] = s;
        }
        __syncthreads();
        int p = tid & 63, cgi = tid >> 6;
        float macc[16] = {};
        for (int s = 0; s < 64; ++s) {
            float vv = vsh[s][p];
            float4 k0 = *(const float4*)&ksh[s][cgi * 16];
            float4 k1 = *(const float4*)&ksh[s][cgi * 16 + 4];
            float4 k2 = *(const float4*)&ksh[s][cgi * 16 + 8];
            float4 k3 = *(const float4*)&ksh[s][cgi * 16 + 12];
            macc[0] += k0.x * vv;  macc[1] += k0.y * vv;  macc[2] += k0.z * vv;  macc[3] += k0.w * vv;
            macc[4] += k1.x * vv;  macc[5] += k1.y * vv;  macc[6] += k1.z * vv;  macc[7] += k1.w * vv;
            macc[8] += k2.x * vv;  macc[9] += k2.y * vv;  macc[10] += k2.z * vv; macc[11] += k2.w * vv;
            macc[12] += k3.x * vv; macc[13] += k3.y * vv; macc[14] += k3.z * vv; macc[15] += k3.w * vv;
        }
        float* o = Mpart + (long long)b * 131072 + (long long)ks * 4096;
        #pragma unroll
        for (int ci = 0; ci < 16; ++ci)
            o[(cgi * 16 + ci) * 64 + p] = macc[ci];
    } else {
        int qb = t - 64;                    // 32 tasks x 128 rows
        long long row0 = (long long)qb * 128;
        #pragma unroll
        for (int i = 0; i < 8; ++i) {
            int pos = tid + 256 * i;        // [row(128)][c4(16)]
            int r = pos >> 4, c4 = (pos & 15) * 4;
            float4 s = *(const float4*)&proj_b[c4];
            long long off = (row0 + r) * 64 + c4;
            #pragma unroll
            for (int sl = 0; sl < 4; ++sl) {
                float4 m = *(const float4*)&qpart[(long long)(sl * 3) * 262144 + off];
                s.x += m.x; s.y += m.y; s.z += m.z; s.w += m.w;
            }
            ushort4 h, l;
            split2(s.x, h.x, l.x); split2(s.y, h.y, l.y);
            split2(s.z, h.z, l.z); split2(s.w, h.w, l.w);
            *(ushort4*)&Qhi[off] = h;
            *(ushort4*)&Qlo[off] = l;
        }
    }
}

// ---- K5: Meff reduce (32 chunks) + G = Meff @ Weff -> GT planes. grid 32.
__global__ __launch_bounds__(256) void gkern(float* __restrict__ ws)
{
    __shared__ float As[64][68], Bs[64][68];
    WS_PTRS(ws)
    (void)wppartT; (void)qpart; (void)WpThi; (void)WpTlo; (void)Qhi; (void)Qlo;
    int t = blockIdx.x, tid = threadIdx.x;
    int colblk = t & 15, b = t >> 4;
    float lam = lamp[0];
    #pragma unroll
    for (int i = 0; i < 4; ++i) {
        int pos = tid + 256 * i;            // 1024 f4 over Meff[64 c][64 p]
        int c = pos >> 4, p4 = (pos & 15) * 4;
        float4 s = {0.f, 0.f, 0.f, 0.f};
        #pragma unroll 8
        for (int sc = 0; sc < 32; ++sc) {
            float4 m = *(const float4*)&Mpart[(long long)b * 131072 + (long long)sc * 4096 + c * 64 + p4];
            s.x += m.x; s.y += m.y; s.z += m.z; s.w += m.w;
        }
        float coef = 0.125f * (c < 32 ? 1.0f : -lam);
        s.x *= coef; s.y *= coef; s.z *= coef; s.w *= coef;
        *(float4*)&As[c][p4] = s;
    }
    #pragma unroll
    for (int i = 0; i < 4; ++i) {
        int pos = tid + 256 * i;
        int p = pos >> 4, e4 = (pos & 15) * 4;
        *(float4*)&Bs[p][e4] = *(const float4*)&Weff[(long long)p * 1024 + colblk * 64 + e4];
    }
    __syncthreads();
    int tx = tid & 15, ty = tid >> 4;
    float acc[4][4] = {};
    #pragma unroll 4
    for (int kk4 = 0; kk4 < 64; kk4 += 4) {
        float4 a4[4], b4[4];
        #pragma unroll
        for (int i = 0; i < 4; ++i) a4[i] = *(const float4*)&As[ty * 4 + i][kk4];
        #pragma unroll
        for (int r = 0; r < 4; ++r) b4[r] = *(const float4*)&Bs[kk4 + r][tx * 4];
        #pragma unroll
        for (int i = 0; i < 4; ++i) {
            acc[i][0] += a4[i].x * b4[0].x + a4[i].y * b4[1].x + a4[i].z * b4[2].x + a4[i].w * b4[3].x;
            acc[i][1] += a4[i].x * b4[0].y + a4[i].y * b4[1].y + a4[i].z * b4[2].y + a4[i].w * b4[3].y;
            acc[i][2] += a4[i].x * b4[0].z + a4[i].y * b4[1].z + a4[i].z * b4[2].z + a4[i].w * b4[3].z;
            acc[i][3] += a4[i].x * b4[0].w + a4[i].y * b4[1].w + a4[i].z * b4[2].w + a4[i].w * b4[3].w;
        }
    }
    #pragma unroll
    for (int i = 0; i < 4; ++i)
        #pragma unroll
        for (int j = 0; j < 4; ++j) {
            ushort_t h, l; split2(acc[i][j], h, l);
            long long idx = (long long)b * 65536 + (long long)(colblk * 64 + tx * 4 + j) * 64 + ty * 4 + i;
            GThi[idx] = h; GTlo[idx] = l;
        }
}

// ---- K6: out = Q @ G. grid 1024.
__global__ __launch_bounds__(256) void outk(float* __restrict__ ws, float* __restrict__ out)
{
    __shared__ __align__(16) ushort_t Ah[4096], Al[4096], Bh[4096], Bl[4096];
    WS_PTRS(ws)
    (void)wppartT; (void)qpart; (void)Mpart; (void)Weff; (void)lamp;
    (void)WpThi; (void)WpTlo;
    int bid = blockIdx.x;
    int rowblk = bid & 31, colblk = (bid >> 5) & 15, b = bid >> 9;
    int tid = threadIdx.x;
    long long row0 = (long long)b * 2048 + rowblk * 64;

    #pragma unroll
    for (int i = 0; i < 2; ++i) {
        int pos = tid + 256 * i;
        int n = pos >> 3, k8 = (pos & 7) * 8;
        int idx = swzA(n, k8);
        long long qsrc = (row0 + n) * 64 + k8;
        long long gsrc = (long long)b * 65536 + (long long)(colblk * 64 + n) * 64 + k8;
        *(short8*)&Ah[idx] = *(const short8*)&Qhi[qsrc];
        *(short8*)&Al[idx] = *(const short8*)&Qlo[qsrc];
        *(short8*)&Bh[idx] = *(const short8*)&GThi[gsrc];
        *(short8*)&Bl[idx] = *(const short8*)&GTlo[gsrc];
    }
    __syncthreads();

    int wave = tid >> 6, lane = tid & 63;
    int rl = lane & 15, kg = lane >> 4;
    f32x4 acc[4] = {};
    int ar = wave * 16 + rl;
    #pragma unroll
    for (int ks = 0; ks < 2; ++ks) {
        int kb = ks * 32 + kg * 8;
        short8 ah = *(const short8*)&Ah[swzA(ar, kb)];
        short8 al = *(const short8*)&Al[swzA(ar, kb)];
        #pragma unroll
        for (int n = 0; n < 4; ++n) {
            int bi = swzA(n * 16 + rl, kb);
            short8 bh = *(const short8*)&Bh[bi];
            short8 bl = *(const short8*)&Bl[bi];
            acc[n] = __builtin_amdgcn_mfma_f32_16x16x32_bf16(ah, bh, acc[n], 0, 0, 0);
            acc[n] = __builtin_amdgcn_mfma_f32_16x16x32_bf16(ah, bl, acc[n], 0, 0, 0);
            acc[n] = __builtin_amdgcn_mfma_f32_16x16x32_bf16(al, bh, acc[n], 0, 0, 0);
        }
    }
    #pragma unroll
    for (int n = 0; n < 4; ++n) {
        int col = colblk * 64 + n * 16 + rl;
        #pragma unroll
        for (int j = 0; j < 4; ++j) {
            int row = rowblk * 64 + wave * 16 + kg * 4 + j;
            out[(long long)b * 2097152 + (long long)row * 1024 + col] = acc[n][j];
        }
    }
}

// ================= launch =================
extern "C" void kernel_launch(void* const* d_in, const int* in_sizes, int n_in,
                              void* d_out, int out_size, void* d_ws, size_t ws_size,
                              hipStream_t stream)
{
    const float* x      = (const float*)d_in[0];
    const float* WQ     = (const float*)d_in[1];
    const float* WK     = (const float*)d_in[2];
    const float* WV     = (const float*)d_in[3];
    const float* RW     = (const float*)d_in[4];
    const float* proj_w = (const float*)d_in[5];
    const float* proj_b = (const float*)d_in[6];
    const float* q1v    = (const float*)d_in[7];
    const float* k1v    = (const float*)d_in[8];
    const float* q2v    = (const float*)d_in[9];
    const float* k2v    = (const float*)d_in[10];
    const float* lam0   = (const float*)d_in[11];
    float* ws  = (float*)d_ws;
    float* out = (float*)d_out;

    dim3 blk(256);
    prep_sk<<<dim3(384), blk, 0, stream>>>(WQ, WK, WV, proj_w, ws);
    wpfix2x<<<dim3(257), blk, 0, stream>>>(RW, q1v, k1v, q2v, k2v, lam0, ws);
    qkv_f<<<dim3(256), blk, 0, stream>>>(x, ws);
    mpartq<<<dim3(96), blk, 0, stream>>>(proj_b, ws);
    gkern<<<dim3(32), blk, 0, stream>>>(ws);
    outk<<<dim3(1024), blk, 0, stream>>>(ws, out);
}